// Round 3
// baseline (516.406 us; speedup 1.0000x reference)
//
#include <hip/hip_runtime.h>
#include <hip/hip_bf16.h>
#include <math.h>

typedef __attribute__((ext_vector_type(8))) short short8;
typedef __attribute__((ext_vector_type(4))) float floatx4;

__device__ __forceinline__ float bf2f(unsigned short u) {
  union { unsigned int i; float f; } v; v.i = ((unsigned int)u) << 16; return v.f;
}
__device__ __forceinline__ unsigned short f2bf(float f) {
  union { float f; unsigned int u; } v; v.f = f;
  unsigned int r = (v.u + 0x7fffu + ((v.u >> 16) & 1u)) >> 16;
  return (unsigned short)r;
}
__device__ __forceinline__ int imin(int a, int b) { return a < b ? a : b; }
__device__ __forceinline__ int imax(int a, int b) { return a > b ? a : b; }
__device__ __forceinline__ int iclamp(int v, int lo, int hi) {
  return v < lo ? lo : (v > hi ? hi : v);
}
__device__ __forceinline__ int nonfin(float f) {
  union { float f; unsigned int u; } v; v.f = f;
  return ((v.u >> 23) & 0xFFu) == 0xFFu;
}

// ---------------- dtype probe: bf16 data vs packed-f32 data ----------------
// Reads first 256 u16 of x. bf16 N(0,1): exponent field in [100,145] for
// ~100% of values. f32 data read as u16: every even u16 is mantissa junk
// (uniform exponent -> ~18% in range) -> count ~151 vs ~256. Threshold 240.
__global__ void k_probe(const void* __restrict__ x, int* dflag) {
  __shared__ int cnt;
  if (threadIdx.x == 0) cnt = 0;
  __syncthreads();
  unsigned short u = ((const unsigned short*)x)[threadIdx.x];
  int e = (u >> 7) & 0xFF;
  int inr = (u == 0) || (e >= 100 && e <= 145);
  atomicAdd(&cnt, inr);
  __syncthreads();
  if (threadIdx.x == 0) dflag[0] = (cnt < 240) ? 1 : 0;
}

// ---------------- flag-branching converters (src -> bf16) ----------------
__global__ void k_cvt(const void* __restrict__ src, unsigned short* __restrict__ dst,
                      int n, const int* __restrict__ dflag, int* flags) {
  int i = blockIdx.x * 256 + threadIdx.x;
  if (i >= n) return;
  int isf = dflag[0];
  unsigned short u = isf ? f2bf(((const float*)src)[i])
                         : ((const unsigned short*)src)[i];
  if (((u >> 7) & 0xFF) == 0xFF) atomicOr(flags, 8);
  dst[i] = u;
}

struct CvtSegs {
  const void* src[10];
  unsigned short* dst[10];
  int len[10];
};
__global__ void k_cvt_small(CvtSegs segs, const int* __restrict__ dflag, int* flags) {
  int seg = blockIdx.x;
  int i = threadIdx.x;
  if (i >= segs.len[seg]) return;
  int isf = dflag[0];
  unsigned short u = isf ? f2bf(((const float*)segs.src[seg])[i])
                         : ((const unsigned short*)segs.src[seg])[i];
  if (((u >> 7) & 0xFF) == 0xFF) atomicOr(flags, 8);
  segs.dst[seg][i] = u;
}

// convert + transpose [R,C] -> [C,R] bf16
__global__ void k_transpose_c(const void* __restrict__ src, unsigned short* __restrict__ out,
                              int R, int C, const int* __restrict__ dflag) {
  int idx = blockIdx.x * 256 + threadIdx.x;
  if (idx >= R * C) return;
  int isf = dflag[0];
  unsigned short u = isf ? f2bf(((const float*)src)[idx])
                         : ((const unsigned short*)src)[idx];
  int r = idx / C, c = idx - r * C;
  out[c * R + r] = u;
}

// ---------------- sentinel: ws too small ----------------
__global__ void k_sentinel(float* out, float val) {
  if (threadIdx.x < 64) out[threadIdx.x] = val;
}

// ---------------- init ----------------
__global__ void k_init(int* deg, float* pool, int* cnt, int* flags, int N) {
  int i = blockIdx.x * 256 + threadIdx.x;
  if (i < N) deg[i] = 1;
  if (i < 64 * 64) pool[i] = 0.f;
  if (i < 64) cnt[i] = 0;
  if (i == 0) flags[0] = 0;
}

// ---------------- degree histogram ----------------
__global__ void k_hist(const int* __restrict__ edst, int* deg, int E, int N) {
  int e = blockIdx.x * 256 + threadIdx.x;
  if (e < E) atomicAdd(&deg[iclamp(edst[e], 0, N - 1)], 1);
}

// ---------------- scan ----------------
__global__ __launch_bounds__(1024) void k_scan1(const int* __restrict__ deg, int* bsum, int N) {
  __shared__ int sm[1024];
  int tid = threadIdx.x;
  int i = blockIdx.x * 1024 + tid;
  sm[tid] = (i < N) ? deg[i] : 0;
  __syncthreads();
  for (int off = 512; off > 0; off >>= 1) {
    if (tid < off) sm[tid] += sm[tid + off];
    __syncthreads();
  }
  if (tid == 0) bsum[blockIdx.x] = sm[0];
}

__global__ void k_scan2(int* bsum, int nb) {
  if (threadIdx.x == 0) {
    int run = 0;
    for (int b = 0; b < nb; ++b) { int t = bsum[b]; bsum[b] = run; run += t; }
  }
}

__global__ __launch_bounds__(1024) void k_scan3(const int* __restrict__ deg,
                                                const int* __restrict__ bsum,
                                                int* rowptr, int* cursor, int N) {
  __shared__ int sm[1024];
  int tid = threadIdx.x;
  int i = blockIdx.x * 1024 + tid;
  int v = (i < N) ? deg[i] : 0;
  sm[tid] = v;
  __syncthreads();
  for (int off = 1; off < 1024; off <<= 1) {
    int t = (tid >= off) ? sm[tid - off] : 0;
    __syncthreads();
    sm[tid] += t;
    __syncthreads();
  }
  if (i < N) {
    int ex = sm[tid] - v + bsum[blockIdx.x];
    rowptr[i] = ex;
    cursor[i] = ex;
    if (i == N - 1) rowptr[N] = ex + v;
  }
}

// ---------------- scatter ----------------
__global__ void k_scatter(const int* __restrict__ esrc, const int* __restrict__ edst,
                          int* cursor, int* colx, int E, int N) {
  int e = blockIdx.x * 256 + threadIdx.x;
  int ET = E + N;
  if (e < ET) {
    int s, d;
    if (e < E) { s = iclamp(esrc[e], 0, N - 1); d = iclamp(edst[e], 0, N - 1); }
    else { s = e - E; d = s; }
    int pos = atomicAdd(&cursor[d], 1);
    pos = iclamp(pos, 0, ET - 1);
    colx[pos] = s;
  }
}

// ---------------- MFMA GEMM: out[N,M] = A[N,K] @ BT[M,K]^T + bias ----------
template <int K>
__global__ __launch_bounds__(256) void k_gemm_bt(const unsigned short* __restrict__ A,
                                                 const unsigned short* __restrict__ BT,
                                                 const unsigned short* __restrict__ bias,
                                                 unsigned short* __restrict__ out,
                                                 int Nrows, int M, int* flags) {
  int lane = threadIdx.x & 63;
  int wave = threadIdx.x >> 6;
  int row0 = blockIdx.x * 16;
  int col0 = blockIdx.y * 64 + wave * 16;
  if (col0 >= M) return;
  int r = lane & 15, q = lane >> 4;
  int ar = imin(row0 + r, Nrows - 1);
  const unsigned short* Ap = A + (size_t)ar * K + q * 8;
  const unsigned short* Bp = BT + (size_t)(col0 + r) * K + q * 8;
  floatx4 acc = {0.f, 0.f, 0.f, 0.f};
#pragma unroll
  for (int k = 0; k < K; k += 32) {
    short8 av = *reinterpret_cast<const short8*>(Ap + k);
    short8 bv = *reinterpret_cast<const short8*>(Bp + k);
    acc = __builtin_amdgcn_mfma_f32_16x16x32_bf16(av, bv, acc, 0, 0, 0);
  }
  float bv = bf2f(bias[col0 + r]);
#pragma unroll
  for (int rr = 0; rr < 4; ++rr) {
    int orow = row0 + q * 4 + rr;
    float v = acc[rr] + bv;
    if (nonfin(v)) { atomicOr(flags, 4); v = 0.f; }
    if (orow < Nrows) out[(size_t)orow * M + col0 + r] = f2bf(v);
  }
}

// ---------------- layer-1 aggregation: H=4, C=64, one wave per dst --------
__global__ __launch_bounds__(256) void k_agg_h4(
    const int* __restrict__ rowptr, const int* __restrict__ colx,
    const unsigned short* __restrict__ xs, const unsigned short* __restrict__ xd,
    const unsigned short* __restrict__ att, const unsigned short* __restrict__ bias,
    unsigned short* __restrict__ hout, int N, int ET, int* flags) {
  int lane = threadIdx.x & 63;
  int dst = (blockIdx.x * 256 + threadIdx.x) >> 6;
  if (dst >= N) return;
  int h = lane >> 4;
  int cb = (lane & 15) << 2;
  int off = h * 64 + cb;
  ushort4 au = *reinterpret_cast<const ushort4*>(att + off);
  ushort4 du = *reinterpret_cast<const ushort4*>(xd + (size_t)dst * 256 + off);
  float a0 = bf2f(au.x), a1 = bf2f(au.y), a2 = bf2f(au.z), a3 = bf2f(au.w);
  float d0 = bf2f(du.x), d1 = bf2f(du.y), d2 = bf2f(du.z), d3 = bf2f(du.w);
  float m = -INFINITY, l = 0.f, o0 = 0.f, o1 = 0.f, o2 = 0.f, o3 = 0.f;
  int beg = imax(rowptr[dst], 0);
  int end = iclamp(rowptr[dst + 1], beg, ET);
  for (int base = beg; base < end; base += 64) {
    int nb = imin(64, end - base);
    int myS = (base + lane < end) ? iclamp(colx[base + lane], 0, N - 1) : 0;
    for (int i = 0; i < nb; ++i) {
      int s = __shfl(myS, i);
      ushort4 vu = *reinterpret_cast<const ushort4*>(xs + (size_t)s * 256 + off);
      float v0 = bf2f(vu.x), v1 = bf2f(vu.y), v2 = bf2f(vu.z), v3 = bf2f(vu.w);
      float t0 = v0 + d0, t1 = v1 + d1, t2 = v2 + d2, t3 = v3 + d3;
      t0 = fmaxf(t0, 0.2f * t0); t1 = fmaxf(t1, 0.2f * t1);
      t2 = fmaxf(t2, 0.2f * t2); t3 = fmaxf(t3, 0.2f * t3);
      float p = fmaf(a0, t0, fmaf(a1, t1, fmaf(a2, t2, a3 * t3)));
      p += __shfl_xor(p, 1); p += __shfl_xor(p, 2);
      p += __shfl_xor(p, 4); p += __shfl_xor(p, 8);
      float mn = fmaxf(m, p);
      float scale = __expf(m - mn);
      float w = __expf(p - mn);
      l = fmaf(l, scale, w);
      o0 = fmaf(o0, scale, w * v0); o1 = fmaf(o1, scale, w * v1);
      o2 = fmaf(o2, scale, w * v2); o3 = fmaf(o3, scale, w * v3);
      m = mn;
    }
  }
  float rl = 1.0f / l;
  ushort4 bu = *reinterpret_cast<const ushort4*>(bias + off);
  float r0 = fmaxf(fmaf(o0, rl, bf2f(bu.x)), 0.f);
  float r1 = fmaxf(fmaf(o1, rl, bf2f(bu.y)), 0.f);
  float r2 = fmaxf(fmaf(o2, rl, bf2f(bu.z)), 0.f);
  float r3 = fmaxf(fmaf(o3, rl, bf2f(bu.w)), 0.f);
  if (nonfin(r0) || nonfin(r1) || nonfin(r2) || nonfin(r3)) {
    atomicOr(flags, 1);
    r0 = r1 = r2 = r3 = 0.f;
  }
  ushort4 res;
  res.x = f2bf(r0); res.y = f2bf(r1); res.z = f2bf(r2); res.w = f2bf(r3);
  *reinterpret_cast<ushort4*>(hout + (size_t)dst * 256 + off) = res;
}

// ---------------- layer-2 aggregation: H=1, C=64, 4 dst per wave ----------
__global__ __launch_bounds__(256) void k_agg_h1(
    const int* __restrict__ rowptr, const int* __restrict__ colx,
    const unsigned short* __restrict__ xs, const unsigned short* __restrict__ xd,
    const unsigned short* __restrict__ att, const unsigned short* __restrict__ bias,
    float* __restrict__ hout, int N, int ET, int* flags) {
  int lane = threadIdx.x & 63;
  int wid = (blockIdx.x * 256 + threadIdx.x) >> 6;
  int g = lane >> 4, sl = lane & 15;
  int dst = wid * 4 + g;
  bool valid = dst < N;
  int dsafe = valid ? dst : 0;
  int cb = sl << 2;
  ushort4 au = *reinterpret_cast<const ushort4*>(att + cb);
  ushort4 du = *reinterpret_cast<const ushort4*>(xd + (size_t)dsafe * 64 + cb);
  float a0 = bf2f(au.x), a1 = bf2f(au.y), a2 = bf2f(au.z), a3 = bf2f(au.w);
  float d0 = bf2f(du.x), d1 = bf2f(du.y), d2 = bf2f(du.z), d3 = bf2f(du.w);
  float m = -INFINITY, l = 0.f, o0 = 0.f, o1 = 0.f, o2 = 0.f, o3 = 0.f;
  int beg = valid ? imax(rowptr[dst], 0) : 0;
  int end = valid ? iclamp(rowptr[dst + 1], beg, ET) : 0;
  for (int base = beg; base < end; base += 16) {
    int nb = imin(16, end - base);
    int myS = (base + sl < end) ? iclamp(colx[base + sl], 0, N - 1) : 0;
    for (int i = 0; i < nb; ++i) {
      int s = __shfl(myS, (g << 4) | i);
      ushort4 vu = *reinterpret_cast<const ushort4*>(xs + (size_t)s * 64 + cb);
      float v0 = bf2f(vu.x), v1 = bf2f(vu.y), v2 = bf2f(vu.z), v3 = bf2f(vu.w);
      float t0 = v0 + d0, t1 = v1 + d1, t2 = v2 + d2, t3 = v3 + d3;
      t0 = fmaxf(t0, 0.2f * t0); t1 = fmaxf(t1, 0.2f * t1);
      t2 = fmaxf(t2, 0.2f * t2); t3 = fmaxf(t3, 0.2f * t3);
      float p = fmaf(a0, t0, fmaf(a1, t1, fmaf(a2, t2, a3 * t3)));
      p += __shfl_xor(p, 1); p += __shfl_xor(p, 2);
      p += __shfl_xor(p, 4); p += __shfl_xor(p, 8);
      float mn = fmaxf(m, p);
      float scale = __expf(m - mn);
      float w = __expf(p - mn);
      l = fmaf(l, scale, w);
      o0 = fmaf(o0, scale, w * v0); o1 = fmaf(o1, scale, w * v1);
      o2 = fmaf(o2, scale, w * v2); o3 = fmaf(o3, scale, w * v3);
      m = mn;
    }
  }
  if (valid) {
    float rl = 1.0f / l;
    ushort4 bu = *reinterpret_cast<const ushort4*>(bias + cb);
    floatx4 res;
    res[0] = fmaf(o0, rl, bf2f(bu.x));
    res[1] = fmaf(o1, rl, bf2f(bu.y));
    res[2] = fmaf(o2, rl, bf2f(bu.z));
    res[3] = fmaf(o3, rl, bf2f(bu.w));
    if (nonfin(res[0]) || nonfin(res[1]) || nonfin(res[2]) || nonfin(res[3])) {
      atomicOr(flags, 2);
      res[0] = res[1] = res[2] = res[3] = 0.f;
    }
    *reinterpret_cast<floatx4*>(hout + (size_t)dst * 64 + cb) = res;
  }
}

// ---------------- mean pool over sorted batch ----------------
__global__ __launch_bounds__(256) void k_pool(const float* __restrict__ h2,
                                              const int* __restrict__ batch,
                                              float* pool, int* cnt, int N) {
  int lane = threadIdx.x & 63;
  int wid = (blockIdx.x * 256 + threadIdx.x) >> 6;
  int n0 = wid * 32;
  if (n0 >= N) return;
  int nend = imin(n0 + 32, N);
  float acc = 0.f;
  int c = 0;
  int gcur = iclamp(batch[n0], 0, 63);
  for (int n = n0; n < nend; ++n) {
    int gg = iclamp(batch[n], 0, 63);
    if (gg != gcur) {
      atomicAdd(&pool[gcur * 64 + lane], acc);
      if (lane == 0) atomicAdd(&cnt[gcur], c);
      acc = 0.f; c = 0; gcur = gg;
    }
    acc += h2[(size_t)n * 64 + lane];
    c++;
  }
  atomicAdd(&pool[gcur * 64 + lane], acc);
  if (lane == 0) atomicAdd(&cnt[gcur], c);
}

// ---------------- final (f32 output + sentinel encoding) ----------------
__global__ void k_final(const float* __restrict__ pool, const int* __restrict__ cnt,
                        const unsigned short* __restrict__ Wlinc,
                        const unsigned short* __restrict__ blinc,
                        float* __restrict__ out,
                        const int* __restrict__ flags, const int* __restrict__ dflag) {
  int g = threadIdx.x;
  if (g >= 64) return;
  int fl = flags[0] & 15;
  float val;
  if (fl) {
    val = 64.f + (float)fl + 16.f * (float)dflag[0];
  } else {
    float inv = 1.f / fmaxf((float)cnt[g], 1.f);
    float s = 0.f;
    for (int c = 0; c < 64; ++c) s += pool[g * 64 + c] * bf2f(Wlinc[c]);
    val = fmaf(s, inv, bf2f(blinc[0]));
    if (nonfin(val)) val = 64.f + 32.f + 16.f * (float)dflag[0];
  }
  out[g] = val;
}

extern "C" void kernel_launch(void* const* d_in, const int* in_sizes, int n_in,
                              void* d_out, int out_size, void* d_ws, size_t ws_size,
                              hipStream_t stream) {
  const void* x     = d_in[0];
  const int*  ei    = (const int*)d_in[1];
  const int*  batch = (const int*)d_in[2];
  const void* Wl1 = d_in[3];  const void* bl1 = d_in[4];
  const void* Wr1 = d_in[5];  const void* br1 = d_in[6];
  const void* att1 = d_in[7]; const void* bias1 = d_in[8];
  const void* Wl2 = d_in[9];  const void* bl2 = d_in[10];
  const void* Wr2 = d_in[11]; const void* br2 = d_in[12];
  const void* att2 = d_in[13]; const void* bias2 = d_in[14];
  const void* Wlin = d_in[15]; const void* blin = d_in[16];
  float* out = (float*)d_out;

  const int F = 128, HC = 256, C2 = 64;
  int N = in_sizes[0] / F;
  int E = in_sizes[1] / 2;
  int ET = E + N;
  const int* esrc = ei;
  const int* edst = ei + E;

  // ---- workspace carve-up: small first, large dense last ----
  char* w = (char*)d_ws;
  auto alloc = [&](size_t bytes) {
    char* p = w;
    w += (bytes + 255) & ~(size_t)255;
    return p;
  };
  int* dflag  = (int*)alloc(4);
  int* flags  = (int*)alloc(4);
  int* rowptr = (int*)alloc((size_t)(N + 1) * 4);
  int* cursor = (int*)alloc((size_t)N * 4);
  int* deg    = (int*)alloc((size_t)N * 4);
  int* bsum   = (int*)alloc(1024 * 4);
  float* pool = (float*)alloc(64 * 64 * 4);
  int* cnt    = (int*)alloc(64 * 4);
  int* colx   = (int*)alloc((size_t)ET * 4);
  unsigned short* smallc = (unsigned short*)alloc(4096);  // converted small vecs
  unsigned short* Wl1T = (unsigned short*)alloc((size_t)F * HC * 2);
  unsigned short* Wr1T = (unsigned short*)alloc((size_t)F * HC * 2);
  unsigned short* Wl2T = (unsigned short*)alloc((size_t)HC * C2 * 2);
  unsigned short* Wr2T = (unsigned short*)alloc((size_t)HC * C2 * 2);
  unsigned short* xs1  = (unsigned short*)alloc((size_t)N * HC * 2);
  unsigned short* xd1  = (unsigned short*)alloc((size_t)N * HC * 2);
  unsigned short* h1   = (unsigned short*)alloc((size_t)N * HC * 2);
  size_t required = (size_t)(w - (char*)d_ws);

  // aliases: x_c lives in h1's slot (dead until agg1); layer-2 staging in xs1/xd1
  unsigned short* x_c = h1;                     // N*F bf16 (12.8 MB <= 25.6 MB)
  unsigned short* xs2 = xs1;
  unsigned short* xd2 = xs1 + (size_t)N * C2;
  float*          h2  = (float*)xd1;

  // converted small vectors layout inside smallc (bf16 elements)
  unsigned short* bl1c   = smallc + 0;     // 256
  unsigned short* br1c   = smallc + 256;   // 256
  unsigned short* att1c  = smallc + 512;   // 256
  unsigned short* bias1c = smallc + 768;   // 256
  unsigned short* bl2c   = smallc + 1024;  // 64
  unsigned short* br2c   = smallc + 1088;  // 64
  unsigned short* att2c  = smallc + 1152;  // 64
  unsigned short* bias2c = smallc + 1216;  // 64
  unsigned short* Wlinc  = smallc + 1280;  // 64
  unsigned short* blinc  = smallc + 1344;  // 1

  if (ws_size < required) {
    k_sentinel<<<1, 64, 0, stream>>>(out, 1000.f + (float)(ws_size >> 20));
    return;
  }

  // ---- probe + init + convert ----
  k_probe<<<1, 256, 0, stream>>>(x, dflag);
  k_init<<<(N + 255) / 256, 256, 0, stream>>>(deg, pool, cnt, flags, N);
  k_cvt<<<(N * F + 255) / 256, 256, 0, stream>>>(x, x_c, N * F, dflag, flags);
  CvtSegs segs;
  const void* ssrc[10] = {bl1, br1, att1, bias1, bl2, br2, att2, bias2, Wlin, blin};
  unsigned short* sdst[10] = {bl1c, br1c, att1c, bias1c, bl2c, br2c, att2c, bias2c, Wlinc, blinc};
  int slen[10] = {256, 256, 256, 256, 64, 64, 64, 64, 64, 1};
  for (int i = 0; i < 10; ++i) { segs.src[i] = ssrc[i]; segs.dst[i] = sdst[i]; segs.len[i] = slen[i]; }
  k_cvt_small<<<10, 256, 0, stream>>>(segs, dflag, flags);
  k_transpose_c<<<(F * HC + 255) / 256, 256, 0, stream>>>(Wl1, Wl1T, F, HC, dflag);
  k_transpose_c<<<(F * HC + 255) / 256, 256, 0, stream>>>(Wr1, Wr1T, F, HC, dflag);
  k_transpose_c<<<(HC * C2 + 255) / 256, 256, 0, stream>>>(Wl2, Wl2T, HC, C2, dflag);
  k_transpose_c<<<(HC * C2 + 255) / 256, 256, 0, stream>>>(Wr2, Wr2T, HC, C2, dflag);

  // ---- CSR build ----
  k_hist<<<(E + 255) / 256, 256, 0, stream>>>(edst, deg, E, N);
  int nb = (N + 1023) / 1024;
  k_scan1<<<nb, 1024, 0, stream>>>(deg, bsum, N);
  k_scan2<<<1, 64, 0, stream>>>(bsum, nb);
  k_scan3<<<nb, 1024, 0, stream>>>(deg, bsum, rowptr, cursor, N);
  k_scatter<<<(ET + 255) / 256, 256, 0, stream>>>(esrc, edst, cursor, colx, E, N);

  // ---- layer 1 (reads x_c; x_c dies when agg1 writes h1 over it) ----
  dim3 g1((N + 15) / 16, HC / 64);
  k_gemm_bt<128><<<g1, 256, 0, stream>>>(x_c, Wl1T, bl1c, xs1, N, HC, flags);
  k_gemm_bt<128><<<g1, 256, 0, stream>>>(x_c, Wr1T, br1c, xd1, N, HC, flags);
  k_agg_h4<<<(N + 3) / 4, 256, 0, stream>>>(rowptr, colx, xs1, xd1, att1c, bias1c, h1, N, ET, flags);

  // ---- layer 2 ----
  dim3 g2((N + 15) / 16, 1);
  k_gemm_bt<256><<<g2, 256, 0, stream>>>(h1, Wl2T, bl2c, xs2, N, C2, flags);
  k_gemm_bt<256><<<g2, 256, 0, stream>>>(h1, Wr2T, br2c, xd2, N, C2, flags);
  k_agg_h1<<<(N + 15) / 16, 256, 0, stream>>>(rowptr, colx, xs2, xd2, att2c, bias2c, h2, N, ET, flags);

  // ---- pool + final ----
  int pw = (N + 31) / 32;
  k_pool<<<(pw + 3) / 4, 256, 0, stream>>>(h2, batch, pool, cnt, N);
  k_final<<<1, 64, 0, stream>>>(pool, cnt, Wlinc, blinc, out, flags, dflag);
}

// Round 4
// 481.494 us; speedup vs baseline: 1.0725x; 1.0725x over previous
//
#include <hip/hip_runtime.h>
#include <hip/hip_bf16.h>
#include <math.h>

typedef __attribute__((ext_vector_type(8))) short short8;
typedef __attribute__((ext_vector_type(4))) float floatx4;

__device__ __forceinline__ float bf2f(unsigned short u) {
  union { unsigned int i; float f; } v; v.i = ((unsigned int)u) << 16; return v.f;
}
__device__ __forceinline__ unsigned short f2bf(float f) {
  union { float f; unsigned int u; } v; v.f = f;
  unsigned int r = (v.u + 0x7fffu + ((v.u >> 16) & 1u)) >> 16;
  return (unsigned short)r;
}
__device__ __forceinline__ int imin(int a, int b) { return a < b ? a : b; }
__device__ __forceinline__ int iclamp(int v, int lo, int hi) {
  return v < lo ? lo : (v > hi ? hi : v);
}
__device__ __forceinline__ float uasf(unsigned int u) {
  union { unsigned int i; float f; } v; v.i = u; return v.f;
}

// ---------------- sentinel: ws too small ----------------
__global__ void k_sentinel(float* out, float val) {
  if (threadIdx.x < 64) out[threadIdx.x] = val;
}

// ---------------- probe (block 0) + init ----------------
__global__ void k_probe_init(const void* __restrict__ x, int* dflag,
                             int* deg, float* pool, int* cnt, int N) {
  int i = blockIdx.x * 256 + threadIdx.x;
  if (i < N) deg[i] = 1;
  if (i < 64 * 64) pool[i] = 0.f;
  if (i < 64) cnt[i] = 0;
  if (blockIdx.x == 0) {
    __shared__ int c;
    if (threadIdx.x == 0) c = 0;
    __syncthreads();
    unsigned short u = ((const unsigned short*)x)[threadIdx.x];
    int e = (u >> 7) & 0xFF;
    atomicAdd(&c, (u == 0) || (e >= 100 && e <= 145));
    __syncthreads();
    if (threadIdx.x == 0) dflag[0] = (c < 240) ? 1 : 0;
  }
}

// ---------------- convert x -> bf16, 8 elems/thread ----------------
__global__ void k_cvt8(const void* __restrict__ src, unsigned short* __restrict__ dst,
                       int n8, const int* __restrict__ dflag) {
  int i = blockIdx.x * 256 + threadIdx.x;
  if (i >= n8) return;
  if (dflag[0]) {
    const float* s = (const float*)src + (size_t)i * 8;
    ushort4 a, b;
    a.x = f2bf(s[0]); a.y = f2bf(s[1]); a.z = f2bf(s[2]); a.w = f2bf(s[3]);
    b.x = f2bf(s[4]); b.y = f2bf(s[5]); b.z = f2bf(s[6]); b.w = f2bf(s[7]);
    ((ushort4*)dst)[i * 2] = a;
    ((ushort4*)dst)[i * 2 + 1] = b;
  } else {
    ((uint4*)dst)[i] = ((const uint4*)src)[i];
  }
}

// ---------------- small-vector conversion ----------------
struct CvtSegs {
  const void* src[10];
  unsigned short* dst[10];
  int len[10];
};
__global__ void k_cvt_small(CvtSegs segs, const int* __restrict__ dflag) {
  int seg = blockIdx.x;
  int i = threadIdx.x;
  if (i >= segs.len[seg]) return;
  segs.dst[seg][i] = dflag[0] ? f2bf(((const float*)segs.src[seg])[i])
                              : ((const unsigned short*)segs.src[seg])[i];
}

// ---------------- all 4 weight transposes in one kernel ----------------
// y=0: Wl1 128x256  y=1: Wr1 128x256  y=2: Wl2 256x64  y=3: Wr2 256x64
__global__ void k_transpose_all(const void* __restrict__ s0, const void* __restrict__ s1,
                                const void* __restrict__ s2, const void* __restrict__ s3,
                                unsigned short* __restrict__ d0, unsigned short* __restrict__ d1,
                                unsigned short* __restrict__ d2, unsigned short* __restrict__ d3,
                                const int* __restrict__ dflag) {
  int y = blockIdx.y;
  int R = (y < 2) ? 128 : 256;
  int C = (y < 2) ? 256 : 64;
  int idx = blockIdx.x * 256 + threadIdx.x;
  if (idx >= R * C) return;
  const void* src = (y == 0) ? s0 : (y == 1) ? s1 : (y == 2) ? s2 : s3;
  unsigned short* dst = (y == 0) ? d0 : (y == 1) ? d1 : (y == 2) ? d2 : d3;
  unsigned short u = dflag[0] ? f2bf(((const float*)src)[idx])
                              : ((const unsigned short*)src)[idx];
  int r = idx / C, c = idx - r * C;
  dst[c * R + r] = u;
}

// ---------------- degree histogram ----------------
__global__ void k_hist(const int* __restrict__ edst, int* deg, int E, int N) {
  int e = blockIdx.x * 256 + threadIdx.x;
  if (e < E) atomicAdd(&deg[iclamp(edst[e], 0, N - 1)], 1);
}

// ---------------- scan ----------------
__global__ __launch_bounds__(1024) void k_scan1(const int* __restrict__ deg, int* bsum, int N) {
  __shared__ int sm[1024];
  int tid = threadIdx.x;
  int i = blockIdx.x * 1024 + tid;
  sm[tid] = (i < N) ? deg[i] : 0;
  __syncthreads();
  for (int off = 512; off > 0; off >>= 1) {
    if (tid < off) sm[tid] += sm[tid + off];
    __syncthreads();
  }
  if (tid == 0) bsum[blockIdx.x] = sm[0];
}

__global__ void k_scan2(int* bsum, int nb) {
  if (threadIdx.x == 0) {
    int run = 0;
    for (int b = 0; b < nb; ++b) { int t = bsum[b]; bsum[b] = run; run += t; }
  }
}

__global__ __launch_bounds__(1024) void k_scan3(const int* __restrict__ deg,
                                                const int* __restrict__ bsum,
                                                int* rowptr, int* cursor, int N) {
  __shared__ int sm[1024];
  int tid = threadIdx.x;
  int i = blockIdx.x * 1024 + tid;
  int v = (i < N) ? deg[i] : 0;
  sm[tid] = v;
  __syncthreads();
  for (int off = 1; off < 1024; off <<= 1) {
    int t = (tid >= off) ? sm[tid - off] : 0;
    __syncthreads();
    sm[tid] += t;
    __syncthreads();
  }
  if (i < N) {
    int ex = sm[tid] - v + bsum[blockIdx.x];
    rowptr[i] = ex;
    cursor[i] = ex;
    if (i == N - 1) rowptr[N] = ex + v;
  }
}

// ---------------- scatter ----------------
__global__ void k_scatter(const int* __restrict__ esrc, const int* __restrict__ edst,
                          int* cursor, int* colx, int E, int N) {
  int e = blockIdx.x * 256 + threadIdx.x;
  int ET = E + N;
  if (e < ET) {
    int s, d;
    if (e < E) { s = iclamp(esrc[e], 0, N - 1); d = iclamp(edst[e], 0, N - 1); }
    else { s = e - E; d = s; }
    int pos = atomicAdd(&cursor[d], 1);
    pos = iclamp(pos, 0, ET - 1);
    colx[pos] = s;
  }
}

// ------- fused dual GEMM: outl = A@BTl^T + bl, outr = A@BTr^T + br --------
// wave w covers cols [w*WT*16, (w+1)*WT*16); block covers 16 rows x 4*WT*16 cols
template <int K, int WT>
__global__ __launch_bounds__(256) void k_gemm2(
    const unsigned short* __restrict__ A,
    const unsigned short* __restrict__ BTl, const unsigned short* __restrict__ BTr,
    const unsigned short* __restrict__ bl, const unsigned short* __restrict__ br,
    unsigned short* __restrict__ outl, unsigned short* __restrict__ outr,
    int Nrows, int M) {
  int lane = threadIdx.x & 63;
  int wave = threadIdx.x >> 6;
  int row0 = blockIdx.x * 16;
  int col0 = wave * (WT * 16);
  int r = lane & 15, q = lane >> 4;
  int ar = imin(row0 + r, Nrows - 1);
  const unsigned short* Ap = A + (size_t)ar * K + q * 8;
  floatx4 accl[WT], accr[WT];
#pragma unroll
  for (int t = 0; t < WT; ++t) {
    accl[t] = (floatx4){0.f, 0.f, 0.f, 0.f};
    accr[t] = (floatx4){0.f, 0.f, 0.f, 0.f};
  }
#pragma unroll
  for (int k = 0; k < K; k += 32) {
    short8 av = *reinterpret_cast<const short8*>(Ap + k);
#pragma unroll
    for (int t = 0; t < WT; ++t) {
      const unsigned short* Bb = (const unsigned short*)0;
      int brow = col0 + t * 16 + r;
      short8 bvl = *reinterpret_cast<const short8*>(BTl + (size_t)brow * K + q * 8 + k);
      short8 bvr = *reinterpret_cast<const short8*>(BTr + (size_t)brow * K + q * 8 + k);
      accl[t] = __builtin_amdgcn_mfma_f32_16x16x32_bf16(av, bvl, accl[t], 0, 0, 0);
      accr[t] = __builtin_amdgcn_mfma_f32_16x16x32_bf16(av, bvr, accr[t], 0, 0, 0);
      (void)Bb;
    }
  }
#pragma unroll
  for (int t = 0; t < WT; ++t) {
    int col = col0 + t * 16 + r;
    float bvl = bf2f(bl[col]);
    float bvr = bf2f(br[col]);
#pragma unroll
    for (int rr = 0; rr < 4; ++rr) {
      int row = row0 + q * 4 + rr;
      if (row < Nrows) {
        outl[(size_t)row * M + col] = f2bf(accl[t][rr] + bvl);
        outr[(size_t)row * M + col] = f2bf(accr[t][rr] + bvr);
      }
    }
  }
}

// ---------------- layer-1 aggregation: H=4, C=64, one wave per dst --------
// lane: head h=lane>>4, channels cb..cb+3. q-trick + clamped no-max softmax.
__global__ __launch_bounds__(256) void k_agg_h4(
    const int* __restrict__ rowptr, const int* __restrict__ colx,
    const unsigned short* __restrict__ xs, const unsigned short* __restrict__ xd,
    const unsigned short* __restrict__ att, const unsigned short* __restrict__ bias,
    unsigned short* __restrict__ hout, int N) {
  int lane = threadIdx.x & 63;
  int dst = (blockIdx.x * 256 + threadIdx.x) >> 6;
  if (dst >= N) return;
  int off = lane << 2;                 // element offset into the 256-row
  unsigned int off2 = (unsigned int)off * 2;
  const char* xsb = (const char*)xs;
  ushort4 au = *reinterpret_cast<const ushort4*>(att + off);
  ushort4 du = *reinterpret_cast<const ushort4*>(xd + (size_t)dst * 256 + off);
  float a0 = bf2f(au.x), a1 = bf2f(au.y), a2 = bf2f(au.z), a3 = bf2f(au.w);
  float d0 = bf2f(du.x), d1 = bf2f(du.y), d2 = bf2f(du.z), d3 = bf2f(du.w);
  float ad0 = a0 * d0, ad1 = a1 * d1, ad2 = a2 * d2, ad3 = a3 * d3;
  float c0 = copysignf(0.4f, a0), c1 = copysignf(0.4f, a1);
  float c2 = copysignf(0.4f, a2), c3 = copysignf(0.4f, a3);
  float l = 0.f, o0 = 0.f, o1 = 0.f, o2 = 0.f, o3 = 0.f;
  int beg = rowptr[dst], end = rowptr[dst + 1];
  // 2-deep software pipeline: colx[e+2] and row(s[e+1]) prefetched
  int s0 = colx[beg];
  uint2 u0 = *reinterpret_cast<const uint2*>(xsb + (((unsigned int)s0 << 9) + off2));
  int snxt = colx[imin(beg + 1, end - 1)];
  for (int e = beg; e < end; ++e) {
    int snn = colx[imin(e + 2, end - 1)];
    uint2 u1 = *reinterpret_cast<const uint2*>(xsb + (((unsigned int)snxt << 9) + off2));
    float v0 = uasf(u0.x << 16), v1 = uasf(u0.x & 0xffff0000u);
    float v2 = uasf(u0.y << 16), v3 = uasf(u0.y & 0xffff0000u);
    float q0 = fmaf(a0, v0, ad0), q1 = fmaf(a1, v1, ad1);
    float q2 = fmaf(a2, v2, ad2), q3 = fmaf(a3, v3, ad3);
    float p = q0 * 0.6f;
    p = fmaf(q1, 0.6f, p); p = fmaf(q2, 0.6f, p); p = fmaf(q3, 0.6f, p);
    p = fmaf(c0, fabsf(q0), p); p = fmaf(c1, fabsf(q1), p);
    p = fmaf(c2, fabsf(q2), p); p = fmaf(c3, fabsf(q3), p);
    p += __shfl_xor(p, 1); p += __shfl_xor(p, 2);
    p += __shfl_xor(p, 4); p += __shfl_xor(p, 8);
    p = fminf(fmaxf(p, -60.f), 60.f);
    float wgt = __expf(p);
    l += wgt;
    o0 = fmaf(wgt, v0, o0); o1 = fmaf(wgt, v1, o1);
    o2 = fmaf(wgt, v2, o2); o3 = fmaf(wgt, v3, o3);
    u0 = u1; snxt = snn;
  }
  float rl = 1.0f / l;
  ushort4 bu = *reinterpret_cast<const ushort4*>(bias + off);
  ushort4 res;
  res.x = f2bf(fmaxf(fmaf(o0, rl, bf2f(bu.x)), 0.f));
  res.y = f2bf(fmaxf(fmaf(o1, rl, bf2f(bu.y)), 0.f));
  res.z = f2bf(fmaxf(fmaf(o2, rl, bf2f(bu.z)), 0.f));
  res.w = f2bf(fmaxf(fmaf(o3, rl, bf2f(bu.w)), 0.f));
  *reinterpret_cast<ushort4*>(hout + (size_t)dst * 256 + off) = res;
}

// ---------------- layer-2 aggregation: H=1, C=64, 4 dst per wave ----------
__global__ __launch_bounds__(256) void k_agg_h1(
    const int* __restrict__ rowptr, const int* __restrict__ colx,
    const unsigned short* __restrict__ xs, const unsigned short* __restrict__ xd,
    const unsigned short* __restrict__ att, const unsigned short* __restrict__ bias,
    float* __restrict__ hout, int N) {
  int lane = threadIdx.x & 63;
  int wid = (blockIdx.x * 256 + threadIdx.x) >> 6;
  int g = lane >> 4, sl = lane & 15;
  int dst = wid * 4 + g;
  bool valid = dst < N;
  int dsafe = valid ? dst : 0;
  int cb = sl << 2;
  unsigned int cb2 = (unsigned int)cb * 2;
  const char* xsb = (const char*)xs;
  ushort4 au = *reinterpret_cast<const ushort4*>(att + cb);
  ushort4 du = *reinterpret_cast<const ushort4*>(xd + (size_t)dsafe * 64 + cb);
  float a0 = bf2f(au.x), a1 = bf2f(au.y), a2 = bf2f(au.z), a3 = bf2f(au.w);
  float d0 = bf2f(du.x), d1 = bf2f(du.y), d2 = bf2f(du.z), d3 = bf2f(du.w);
  float ad0 = a0 * d0, ad1 = a1 * d1, ad2 = a2 * d2, ad3 = a3 * d3;
  float c0 = copysignf(0.4f, a0), c1 = copysignf(0.4f, a1);
  float c2 = copysignf(0.4f, a2), c3 = copysignf(0.4f, a3);
  float l = 0.f, o0 = 0.f, o1 = 0.f, o2 = 0.f, o3 = 0.f;
  int beg = valid ? rowptr[dst] : 0;
  int end = valid ? rowptr[dst + 1] : 0;
  if (end > beg) {
    int s0 = colx[beg];
    uint2 u0 = *reinterpret_cast<const uint2*>(xsb + (((unsigned int)s0 << 7) + cb2));
    int snxt = colx[imin(beg + 1, end - 1)];
    for (int e = beg; e < end; ++e) {
      int snn = colx[imin(e + 2, end - 1)];
      uint2 u1 = *reinterpret_cast<const uint2*>(xsb + (((unsigned int)snxt << 7) + cb2));
      float v0 = uasf(u0.x << 16), v1 = uasf(u0.x & 0xffff0000u);
      float v2 = uasf(u0.y << 16), v3 = uasf(u0.y & 0xffff0000u);
      float q0 = fmaf(a0, v0, ad0), q1 = fmaf(a1, v1, ad1);
      float q2 = fmaf(a2, v2, ad2), q3 = fmaf(a3, v3, ad3);
      float p = q0 * 0.6f;
      p = fmaf(q1, 0.6f, p); p = fmaf(q2, 0.6f, p); p = fmaf(q3, 0.6f, p);
      p = fmaf(c0, fabsf(q0), p); p = fmaf(c1, fabsf(q1), p);
      p = fmaf(c2, fabsf(q2), p); p = fmaf(c3, fabsf(q3), p);
      p += __shfl_xor(p, 1); p += __shfl_xor(p, 2);
      p += __shfl_xor(p, 4); p += __shfl_xor(p, 8);
      p = fminf(fmaxf(p, -60.f), 60.f);
      float wgt = __expf(p);
      l += wgt;
      o0 = fmaf(wgt, v0, o0); o1 = fmaf(wgt, v1, o1);
      o2 = fmaf(wgt, v2, o2); o3 = fmaf(wgt, v3, o3);
      u0 = u1; snxt = snn;
    }
  }
  if (valid) {
    float rl = 1.0f / l;
    ushort4 bu = *reinterpret_cast<const ushort4*>(bias + cb);
    floatx4 res;
    res[0] = fmaf(o0, rl, bf2f(bu.x));
    res[1] = fmaf(o1, rl, bf2f(bu.y));
    res[2] = fmaf(o2, rl, bf2f(bu.z));
    res[3] = fmaf(o3, rl, bf2f(bu.w));
    *reinterpret_cast<floatx4*>(hout + (size_t)dst * 64 + cb) = res;
  }
}

// ---------------- mean pool over sorted batch ----------------
__global__ __launch_bounds__(256) void k_pool(const float* __restrict__ h2,
                                              const int* __restrict__ batch,
                                              float* pool, int* cnt, int N) {
  int lane = threadIdx.x & 63;
  int wid = (blockIdx.x * 256 + threadIdx.x) >> 6;
  int n0 = wid * 32;
  if (n0 >= N) return;
  int nend = imin(n0 + 32, N);
  float acc = 0.f;
  int c = 0;
  int gcur = iclamp(batch[n0], 0, 63);
  for (int n = n0; n < nend; ++n) {
    int gg = iclamp(batch[n], 0, 63);
    if (gg != gcur) {
      atomicAdd(&pool[gcur * 64 + lane], acc);
      if (lane == 0) atomicAdd(&cnt[gcur], c);
      acc = 0.f; c = 0; gcur = gg;
    }
    acc += h2[(size_t)n * 64 + lane];
    c++;
  }
  atomicAdd(&pool[gcur * 64 + lane], acc);
  if (lane == 0) atomicAdd(&cnt[gcur], c);
}

// ---------------- final ----------------
__global__ void k_final(const float* __restrict__ pool, const int* __restrict__ cnt,
                        const unsigned short* __restrict__ Wlinc,
                        const unsigned short* __restrict__ blinc,
                        float* __restrict__ out) {
  int g = threadIdx.x;
  if (g >= 64) return;
  float inv = 1.f / fmaxf((float)cnt[g], 1.f);
  float s = 0.f;
  for (int c = 0; c < 64; ++c) s += pool[g * 64 + c] * bf2f(Wlinc[c]);
  out[g] = fmaf(s, inv, bf2f(blinc[0]));
}

extern "C" void kernel_launch(void* const* d_in, const int* in_sizes, int n_in,
                              void* d_out, int out_size, void* d_ws, size_t ws_size,
                              hipStream_t stream) {
  const void* x     = d_in[0];
  const int*  ei    = (const int*)d_in[1];
  const int*  batch = (const int*)d_in[2];
  const void* Wl1 = d_in[3];  const void* bl1 = d_in[4];
  const void* Wr1 = d_in[5];  const void* br1 = d_in[6];
  const void* att1 = d_in[7]; const void* bias1 = d_in[8];
  const void* Wl2 = d_in[9];  const void* bl2 = d_in[10];
  const void* Wr2 = d_in[11]; const void* br2 = d_in[12];
  const void* att2 = d_in[13]; const void* bias2 = d_in[14];
  const void* Wlin = d_in[15]; const void* blin = d_in[16];
  float* out = (float*)d_out;

  const int F = 128, HC = 256, C2 = 64;
  int N = in_sizes[0] / F;
  int E = in_sizes[1] / 2;
  int ET = E + N;
  const int* esrc = ei;
  const int* edst = ei + E;

  // ---- workspace carve-up: small first, large dense last ----
  char* w = (char*)d_ws;
  auto alloc = [&](size_t bytes) {
    char* p = w;
    w += (bytes + 255) & ~(size_t)255;
    return p;
  };
  int* dflag  = (int*)alloc(4);
  int* rowptr = (int*)alloc((size_t)(N + 1) * 4);
  int* cursor = (int*)alloc((size_t)N * 4);
  int* deg    = (int*)alloc((size_t)N * 4);
  int* bsum   = (int*)alloc(1024 * 4);
  float* pool = (float*)alloc(64 * 64 * 4);
  int* cnt    = (int*)alloc(64 * 4);
  int* colx   = (int*)alloc((size_t)ET * 4);
  unsigned short* smallc = (unsigned short*)alloc(4096);
  unsigned short* Wl1T = (unsigned short*)alloc((size_t)F * HC * 2);
  unsigned short* Wr1T = (unsigned short*)alloc((size_t)F * HC * 2);
  unsigned short* Wl2T = (unsigned short*)alloc((size_t)HC * C2 * 2);
  unsigned short* Wr2T = (unsigned short*)alloc((size_t)HC * C2 * 2);
  unsigned short* xs1  = (unsigned short*)alloc((size_t)N * HC * 2);
  unsigned short* xd1  = (unsigned short*)alloc((size_t)N * HC * 2);
  unsigned short* h1   = (unsigned short*)alloc((size_t)N * HC * 2);
  size_t required = (size_t)(w - (char*)d_ws);

  // aliases: x_c in h1's slot (dead until agg1 writes h1); layer-2 in xs1/xd1
  unsigned short* x_c = h1;
  unsigned short* xs2 = xs1;
  unsigned short* xd2 = xs1 + (size_t)N * C2;
  float*          h2  = (float*)xd1;

  unsigned short* bl1c   = smallc + 0;
  unsigned short* br1c   = smallc + 256;
  unsigned short* att1c  = smallc + 512;
  unsigned short* bias1c = smallc + 768;
  unsigned short* bl2c   = smallc + 1024;
  unsigned short* br2c   = smallc + 1088;
  unsigned short* att2c  = smallc + 1152;
  unsigned short* bias2c = smallc + 1216;
  unsigned short* Wlinc  = smallc + 1280;
  unsigned short* blinc  = smallc + 1344;

  if (ws_size < required) {
    k_sentinel<<<1, 64, 0, stream>>>(out, 1000.f + (float)(ws_size >> 20));
    return;
  }

  // ---- probe + init + conversions ----
  k_probe_init<<<(N + 255) / 256, 256, 0, stream>>>(x, dflag, deg, pool, cnt, N);
  k_cvt8<<<(N * F / 8 + 255) / 256, 256, 0, stream>>>(x, x_c, N * F / 8, dflag);
  CvtSegs segs;
  const void* ssrc[10] = {bl1, br1, att1, bias1, bl2, br2, att2, bias2, Wlin, blin};
  unsigned short* sdst[10] = {bl1c, br1c, att1c, bias1c, bl2c, br2c, att2c, bias2c, Wlinc, blinc};
  int slen[10] = {256, 256, 256, 256, 64, 64, 64, 64, 64, 1};
  for (int i = 0; i < 10; ++i) { segs.src[i] = ssrc[i]; segs.dst[i] = sdst[i]; segs.len[i] = slen[i]; }
  k_cvt_small<<<10, 256, 0, stream>>>(segs, dflag);
  dim3 tg((128 * 256 + 255) / 256, 4);
  k_transpose_all<<<tg, 256, 0, stream>>>(Wl1, Wr1, Wl2, Wr2, Wl1T, Wr1T, Wl2T, Wr2T, dflag);

  // ---- CSR build ----
  k_hist<<<(E + 255) / 256, 256, 0, stream>>>(edst, deg, E, N);
  int nb = (N + 1023) / 1024;
  k_scan1<<<nb, 1024, 0, stream>>>(deg, bsum, N);
  k_scan2<<<1, 64, 0, stream>>>(bsum, nb);
  k_scan3<<<nb, 1024, 0, stream>>>(deg, bsum, rowptr, cursor, N);
  k_scatter<<<(ET + 255) / 256, 256, 0, stream>>>(esrc, edst, cursor, colx, E, N);

  // ---- layer 1: fused dual GEMM + aggregation ----
  k_gemm2<128, 4><<<(N + 15) / 16, 256, 0, stream>>>(x_c, Wl1T, Wr1T, bl1c, br1c,
                                                     xs1, xd1, N, HC);
  k_agg_h4<<<(N + 3) / 4, 256, 0, stream>>>(rowptr, colx, xs1, xd1, att1c, bias1c, h1, N);

  // ---- layer 2 ----
  k_gemm2<256, 1><<<(N + 15) / 16, 256, 0, stream>>>(h1, Wl2T, Wr2T, bl2c, br2c,
                                                     xs2, xd2, N, C2);
  k_agg_h1<<<(N + 15) / 16, 256, 0, stream>>>(rowptr, colx, xs2, xd2, att2c, bias2c, h2, N);

  // ---- pool + final ----
  int pw = (N + 31) / 32;
  k_pool<<<(pw + 3) / 4, 256, 0, stream>>>(h2, batch, pool, cnt, N);
  k_final<<<1, 64, 0, stream>>>(pool, cnt, Wlinc, blinc, out);
}